// Round 1
// baseline (209.155 us; speedup 1.0000x reference)
//
#include <hip/hip_runtime.h>
#include <hip/hip_bf16.h>

// Dead-code-eliminated forward: outputs (pred, act) depend ONLY on
//   ctx = context_batch @ ctx_w + ctx_b
//   v    = ctx @ ca_wv + ca_bv          (cross-attn softmax over 1 key == 1.0)
//   last = v @ ca_wo + ca_bo
//   pred = last @ pred_w[sid] + pred_b[sid];  act likewise.
// The embedding + 4 transformer layers + q/k projections never reach the output.

#define DD 512
#define BB 16
#define OO 64

// Runtime dtype flag: 1 = float tensors delivered as bf16, 0 = fp32.
template<bool BF>
__device__ __forceinline__ float LD(const void* p, int i) {
  if constexpr (BF)
    return __bfloat162float(reinterpret_cast<const __hip_bfloat16*>(p)[i]);
  else
    return reinterpret_cast<const float*>(p)[i];
}

// Detect bf16 vs fp32 packing of emb_table (VOCAB x D of N(0,1)).
// bf16-packed: low 16 bits of each dword are a plausible bf16 (exp ~110..135).
// fp32-packed: low 16 bits are uniform mantissa bits (plausible ~10% of the time).
__global__ void k_detect(const unsigned int* emb, int* flag) {
  unsigned int w = emb[threadIdx.x];          // 64 dwords = 256 B, safe either way
  unsigned int lo = w & 0xffffu;
  unsigned int ex = (lo >> 7) & 0xffu;        // bf16 exponent field of the low half
  bool ok = (ex >= 110u && ex <= 135u) || ((lo & 0x7fffu) == 0u);
  unsigned long long m = __ballot(ok);
  if (threadIdx.x == 0) *flag = (__popcll(m) >= 48) ? 1 : 0;
}

// v[b, j] = sum_d ctx[b, d] * ca_wv[d, j] + ca_bv[j],
// ctx[b, d] = cb[b,0]*ctx_w[0,d] + cb[b,1]*ctx_w[1,d] + ctx_b[d]
template<bool BF>
__device__ __forceinline__ void v_impl(const void* cb, const void* cw, const void* cbias,
                                       const void* wv, const void* bv, float* v) {
  __shared__ float ctx_s[DD];
  const int b = blockIdx.y;
  const int j = blockIdx.x * 256 + threadIdx.x;
  const float c0 = LD<BF>(cb, 2 * b), c1 = LD<BF>(cb, 2 * b + 1);
  for (int d = threadIdx.x; d < DD; d += 256)
    ctx_s[d] = c0 * LD<BF>(cw, d) + c1 * LD<BF>(cw, DD + d) + LD<BF>(cbias, d);
  __syncthreads();
  float acc = LD<BF>(bv, j);
#pragma unroll 8
  for (int d = 0; d < DD; ++d)
    acc = fmaf(ctx_s[d], LD<BF>(wv, d * DD + j), acc);  // coalesced across j
  v[b * DD + j] = acc;
}

__global__ void k_v(const void* cb, const void* cw, const void* cbias,
                    const void* wv, const void* bv, float* v, const int* flag) {
  if (*flag) v_impl<true>(cb, cw, cbias, wv, bv, v);
  else       v_impl<false>(cb, cw, cbias, wv, bv, v);
}

// last[b, j] = sum_d v[b, d] * ca_wo[d, j] + ca_bo[j]
template<bool BF>
__device__ __forceinline__ void o_impl(const float* v, const void* wo, const void* bo,
                                       float* last) {
  __shared__ float vs[DD];
  const int b = blockIdx.y;
  const int j = blockIdx.x * 256 + threadIdx.x;
  for (int d = threadIdx.x; d < DD; d += 256) vs[d] = v[b * DD + d];
  __syncthreads();
  float acc = LD<BF>(bo, j);
#pragma unroll 8
  for (int d = 0; d < DD; ++d)
    acc = fmaf(vs[d], LD<BF>(wo, d * DD + j), acc);
  last[b * DD + j] = acc;
}

__global__ void k_o(const float* v, const void* wo, const void* bo, float* last,
                    const int* flag) {
  if (*flag) o_impl<true>(v, wo, bo, last);
  else       o_impl<false>(v, wo, bo, last);
}

// pred[b, o] = sum_d last[b, d] * pred_w[sid[b], d, o] + pred_b[sid[b], o]; act likewise.
// d_out layout: pred (B*OUT floats) then act (B*OUT), row-major.
template<bool BF>
__device__ __forceinline__ void head_impl(const float* last, const int* sid,
                                          const void* pw, const void* pb,
                                          const void* aw, const void* ab, void* out) {
  __shared__ float ls[DD];
  const int b = blockIdx.x;
  for (int d = threadIdx.x; d < DD; d += 128) ls[d] = last[b * DD + d];
  __syncthreads();
  const int half = threadIdx.x >> 6;  // 0 = pred, 1 = act
  const int o = threadIdx.x & 63;
  const int s = sid[b];
  const void* w = half ? aw : pw;
  const void* bias = half ? ab : pb;
  float acc = LD<BF>(bias, s * OO + o);
#pragma unroll 8
  for (int d = 0; d < DD; ++d)
    acc = fmaf(ls[d], LD<BF>(w, (s * DD + d) * OO + o), acc);
  const int oi = half * (BB * OO) + b * OO + o;
  if constexpr (BF)
    reinterpret_cast<__hip_bfloat16*>(out)[oi] = __float2bfloat16(acc);
  else
    reinterpret_cast<float*>(out)[oi] = acc;
}

__global__ void k_head(const float* last, const int* sid, const void* pw, const void* pb,
                       const void* aw, const void* ab, void* out, const int* flag) {
  if (*flag) head_impl<true>(last, sid, pw, pb, aw, ab, out);
  else       head_impl<false>(last, sid, pw, pb, aw, ab, out);
}

extern "C" void kernel_launch(void* const* d_in, const int* in_sizes, int n_in,
                              void* d_out, int out_size, void* d_ws, size_t ws_size,
                              hipStream_t stream) {
  // setup_inputs() order:
  // 0 x_batch 1 context_batch 2 specialist_ids 3 emb_table 4 wqkv 5 bqkv 6 wo 7 bo
  // 8 ln1_g 9 ln1_b 10 w1 11 b1 12 w2 13 b2 14 ln2_g 15 ln2_b 16 ctx_w 17 ctx_b
  // 18 ca_wq 19 ca_bq 20 ca_wk 21 ca_bk 22 ca_wv 23 ca_bv 24 ca_wo 25 ca_bo
  // 26 pred_w 27 pred_b 28 act_w 29 act_b
  const void* cb    = d_in[1];
  const int*  sid   = reinterpret_cast<const int*>(d_in[2]);
  const void* emb   = d_in[3];
  const void* cw    = d_in[16];
  const void* cbias = d_in[17];
  const void* wv    = d_in[22];
  const void* bv    = d_in[23];
  const void* wo    = d_in[24];
  const void* bo    = d_in[25];
  const void* pw    = d_in[26];
  const void* pb    = d_in[27];
  const void* aw    = d_in[28];
  const void* ab    = d_in[29];

  float* v    = reinterpret_cast<float*>(d_ws);            // 16*512 f32
  float* last = v + BB * DD;                               // 16*512 f32
  int*   flag = reinterpret_cast<int*>(last + BB * DD);    // 1 int

  k_detect<<<1, 64, 0, stream>>>(reinterpret_cast<const unsigned int*>(emb), flag);
  k_v<<<dim3(2, BB), 256, 0, stream>>>(cb, cw, cbias, wv, bv, v, flag);
  k_o<<<dim3(2, BB), 256, 0, stream>>>(v, wo, bo, last, flag);
  k_head<<<BB, 128, 0, stream>>>(last, sid, pw, pb, aw, ab, d_out, flag);
}

// Round 2
// 161.209 us; speedup vs baseline: 1.2974x; 1.2974x over previous
//
#include <hip/hip_runtime.h>
#include <hip/hip_bf16.h>

// Dead-code-eliminated forward (verified round 1: passed, absmax 7.5e-9, fp32 inputs).
// Cross-attention has a single key/value -> softmax == 1 -> outputs depend only on:
//   ctx  = context_batch @ ctx_w + ctx_b          (2 -> 512)
//   v    = ctx @ ca_wv + ca_bv                    (512x512)
//   last = v @ ca_wo + ca_bo                      (512x512)
//   pred = last @ pred_w[sid] + pred_b[sid]; act likewise (512x64 each)
// Embedding, all 4 transformer layers, and q/k projections never reach the output.
// Single fused kernel: 16 blocks (one per batch element) x 1024 threads.

#define DD 512
#define BB 16
#define OO 64

__global__ __launch_bounds__(1024) void k_fused(
    const float* __restrict__ cb,     // context_batch  [B,2]
    const float* __restrict__ cw,     // ctx_w          [2,D]
    const float* __restrict__ cbias,  // ctx_b          [D]
    const float* __restrict__ wv,     // ca_wv          [D,D]
    const float* __restrict__ bv,     // ca_bv          [D]
    const float* __restrict__ wo,     // ca_wo          [D,D]
    const float* __restrict__ bo,     // ca_bo          [D]
    const int*   __restrict__ sid,    // specialist_ids [B]
    const float* __restrict__ pw,     // pred_w         [NS,D,OUT]
    const float* __restrict__ pb,     // pred_b         [NS,OUT]
    const float* __restrict__ aw,     // act_w          [NS,D,OUT]
    const float* __restrict__ ab,     // act_b          [NS,OUT]
    float*       __restrict__ out) {  // [2,B,OUT]  (pred then act)
  __shared__ float ctx_s[DD];
  __shared__ float buf_s[DD];
  __shared__ float red_s[1024];

  const int b   = blockIdx.x;
  const int tid = threadIdx.x;

  // ---- phase 1: ctx = cb[b] @ ctx_w + ctx_b ----
  if (tid < DD) {
    const float c0 = cb[2 * b], c1 = cb[2 * b + 1];
    ctx_s[tid] = fmaf(c0, cw[tid], fmaf(c1, cw[DD + tid], cbias[tid]));
  }
  __syncthreads();

  // ---- phase 2: v = ctx @ ca_wv + ca_bv (2 threads per column) ----
  {
    const int j = tid & (DD - 1);
    const int h = tid >> 9;                 // 0 or 1: which half of d
    float acc = h ? 0.0f : bv[j];
    const int d0 = h * (DD / 2);
#pragma unroll 8
    for (int d = 0; d < DD / 2; ++d)
      acc = fmaf(ctx_s[d0 + d], wv[(d0 + d) * DD + j], acc);
    red_s[tid] = acc;
  }
  __syncthreads();
  if (tid < DD) buf_s[tid] = red_s[tid] + red_s[tid + DD];  // buf_s = v
  __syncthreads();

  // ---- phase 3: last = v @ ca_wo + ca_bo ----
  {
    const int j = tid & (DD - 1);
    const int h = tid >> 9;
    float acc = h ? 0.0f : bo[j];
    const int d0 = h * (DD / 2);
#pragma unroll 8
    for (int d = 0; d < DD / 2; ++d)
      acc = fmaf(buf_s[d0 + d], wo[(d0 + d) * DD + j], acc);
    red_s[tid] = acc;
  }
  __syncthreads();
  if (tid < DD) ctx_s[tid] = red_s[tid] + red_s[tid + DD];  // ctx_s = last (reuse)
  __syncthreads();

  // ---- phase 4: heads. 128 outputs (64 pred + 64 act), 8 d-partitions each ----
  {
    const int oi   = tid & 127;       // 0..63 pred, 64..127 act
    const int part = tid >> 7;        // 0..7
    const int half = oi >> 6;
    const int o    = oi & 63;
    const int s    = sid[b];
    const float* w    = half ? aw : pw;
    const float* bias = half ? ab : pb;
    float acc = (part == 0) ? bias[s * OO + o] : 0.0f;
    const int d0 = part * (DD / 8);
#pragma unroll 8
    for (int d = 0; d < DD / 8; ++d)
      acc = fmaf(ctx_s[d0 + d], w[(s * DD + d0 + d) * OO + o], acc);
    red_s[tid] = acc;
  }
  __syncthreads();
  if (tid < 128) {
    float acc = 0.0f;
#pragma unroll
    for (int p = 0; p < 8; ++p) acc += red_s[tid + 128 * p];
    const int half = tid >> 6, o = tid & 63;
    out[half * (BB * OO) + b * OO + o] = acc;
  }
}

extern "C" void kernel_launch(void* const* d_in, const int* in_sizes, int n_in,
                              void* d_out, int out_size, void* d_ws, size_t ws_size,
                              hipStream_t stream) {
  // setup_inputs() order:
  // 0 x_batch 1 context_batch 2 specialist_ids 3 emb_table 4 wqkv 5 bqkv 6 wo 7 bo
  // 8 ln1_g 9 ln1_b 10 w1 11 b1 12 w2 13 b2 14 ln2_g 15 ln2_b 16 ctx_w 17 ctx_b
  // 18 ca_wq 19 ca_bq 20 ca_wk 21 ca_bk 22 ca_wv 23 ca_bv 24 ca_wo 25 ca_bo
  // 26 pred_w 27 pred_b 28 act_w 29 act_b
  k_fused<<<BB, 1024, 0, stream>>>(
      reinterpret_cast<const float*>(d_in[1]),
      reinterpret_cast<const float*>(d_in[16]),
      reinterpret_cast<const float*>(d_in[17]),
      reinterpret_cast<const float*>(d_in[22]),
      reinterpret_cast<const float*>(d_in[23]),
      reinterpret_cast<const float*>(d_in[24]),
      reinterpret_cast<const float*>(d_in[25]),
      reinterpret_cast<const int*>(d_in[2]),
      reinterpret_cast<const float*>(d_in[26]),
      reinterpret_cast<const float*>(d_in[27]),
      reinterpret_cast<const float*>(d_in[28]),
      reinterpret_cast<const float*>(d_in[29]),
      reinterpret_cast<float*>(d_out));
}

// Round 3
// 159.578 us; speedup vs baseline: 1.3107x; 1.0102x over previous
//
#include <hip/hip_runtime.h>
#include <hip/hip_bf16.h>

// Dead-code-eliminated forward (verified: passed, absmax 7.5e-9, fp32 inputs).
// Cross-attention has a single key/value -> softmax == 1 -> outputs depend only on:
//   ctx  = context_batch @ ctx_w + ctx_b          (2 -> 512)
//   v    = ctx @ ca_wv + ca_bv                    (512x512)
//   last = v @ ca_wo + ca_bo                      (512x512)
//   pred = last @ pred_w[sid] + pred_b[sid]; act likewise (512x64 each)
// Single fused kernel, 16 blocks x 1024 threads. Round-2 rework: float4 weight
// streaming + 8-way d-split + unroll-16 for ~16 outstanding loads/thread
// (latency-bound fix: 44.5us kernel was scalar loads w/ unroll-8).

#define DD 512
#define BB 16
#define OO 64

__global__ __launch_bounds__(1024) void k_fused(
    const float* __restrict__ cb,     // context_batch  [B,2]
    const float* __restrict__ cw,     // ctx_w          [2,D]
    const float* __restrict__ cbias,  // ctx_b          [D]
    const float* __restrict__ wv,     // ca_wv          [D,D]
    const float* __restrict__ bv,     // ca_bv          [D]
    const float* __restrict__ wo,     // ca_wo          [D,D]
    const float* __restrict__ bo,     // ca_bo          [D]
    const int*   __restrict__ sid,    // specialist_ids [B]
    const float* __restrict__ pw,     // pred_w         [NS,D,OUT]
    const float* __restrict__ pb,     // pred_b         [NS,OUT]
    const float* __restrict__ aw,     // act_w          [NS,D,OUT]
    const float* __restrict__ ab,     // act_b          [NS,OUT]
    float*       __restrict__ out) {  // [2,B,OUT]  (pred then act)
  __shared__ float ctx_s[DD];         // ctx, later reused as `last`
  __shared__ float vv_s[DD];          // v
  __shared__ float bv_s[DD];
  __shared__ float bo_s[DD];
  __shared__ float hb_s[2 * OO];      // pred_b / act_b rows for this block's sid
  __shared__ float red_s[8 * DD];     // 16 KB partial-sum buffer (reused per phase)

  const int b   = blockIdx.x;
  const int tid = threadIdx.x;
  const int s   = sid[b];

  // ---- phase 1: lower 512 threads compute ctx; upper 512 prefetch biases ----
  if (tid < DD) {
    const float c0 = cb[2 * b], c1 = cb[2 * b + 1];
    ctx_s[tid] = fmaf(c0, cw[tid], fmaf(c1, cw[DD + tid], cbias[tid]));
  } else {
    const int t = tid - DD;
    bv_s[t] = bv[t];
    bo_s[t] = bo[t];
    if (t < 2 * OO) hb_s[t] = (t < OO) ? pb[s * OO + t] : ab[s * OO + (t - OO)];
  }
  __syncthreads();

  // ---- phase 2: v = ctx @ ca_wv + ca_bv ----
  // thread = (p, g): p in [0,8) d-partition of 64, g in [0,128) float4 column group
  {
    const int g = tid & 127, p = tid >> 7, d0 = p * 64;
    const float4* w = reinterpret_cast<const float4*>(wv) + d0 * 128 + g;
    float4 acc = {0.f, 0.f, 0.f, 0.f};
#pragma unroll 16
    for (int d = 0; d < 64; ++d) {
      const float c = ctx_s[d0 + d];
      const float4 wr = w[d * 128];
      acc.x = fmaf(c, wr.x, acc.x);
      acc.y = fmaf(c, wr.y, acc.y);
      acc.z = fmaf(c, wr.z, acc.z);
      acc.w = fmaf(c, wr.w, acc.w);
    }
    reinterpret_cast<float4*>(red_s)[p * 128 + g] = acc;
  }
  __syncthreads();
  if (tid < DD) {
    float a = bv_s[tid];
#pragma unroll
    for (int p = 0; p < 8; ++p) a += red_s[p * DD + tid];
    vv_s[tid] = a;
  }
  __syncthreads();

  // ---- phase 3: last = v @ ca_wo + ca_bo ----
  {
    const int g = tid & 127, p = tid >> 7, d0 = p * 64;
    const float4* w = reinterpret_cast<const float4*>(wo) + d0 * 128 + g;
    float4 acc = {0.f, 0.f, 0.f, 0.f};
#pragma unroll 16
    for (int d = 0; d < 64; ++d) {
      const float c = vv_s[d0 + d];
      const float4 wr = w[d * 128];
      acc.x = fmaf(c, wr.x, acc.x);
      acc.y = fmaf(c, wr.y, acc.y);
      acc.z = fmaf(c, wr.z, acc.z);
      acc.w = fmaf(c, wr.w, acc.w);
    }
    reinterpret_cast<float4*>(red_s)[p * 128 + g] = acc;
  }
  __syncthreads();
  if (tid < DD) {
    float a = bo_s[tid];
#pragma unroll
    for (int p = 0; p < 8; ++p) a += red_s[p * DD + tid];
    ctx_s[tid] = a;  // ctx_s now holds `last`
  }
  __syncthreads();

  // ---- phase 4: pred/act heads ----
  // thread = (half, p, og): half = pred/act, p in [0,32) d-partition of 16,
  // og in [0,16) float4 output group.
  {
    const int half = tid >> 9, t = tid & 511;
    const int og = t & 15, p = t >> 4, d0 = p * 16;
    const float* wsel = half ? aw : pw;
    const float4* w = reinterpret_cast<const float4*>(wsel) + (s * DD + d0) * 16 + og;
    float4 acc = {0.f, 0.f, 0.f, 0.f};
#pragma unroll
    for (int d = 0; d < 16; ++d) {
      const float c = ctx_s[d0 + d];
      const float4 wr = w[d * 16];
      acc.x = fmaf(c, wr.x, acc.x);
      acc.y = fmaf(c, wr.y, acc.y);
      acc.z = fmaf(c, wr.z, acc.z);
      acc.w = fmaf(c, wr.w, acc.w);
    }
    reinterpret_cast<float4*>(red_s)[half * 512 + p * 16 + og] = acc;
  }
  __syncthreads();
  if (tid < 2 * OO) {
    const int half = tid >> 6, o = tid & 63;
    float a = hb_s[tid];
#pragma unroll
    for (int p = 0; p < 32; ++p) a += red_s[half * 2048 + p * 64 + o];
    out[half * (BB * OO) + b * OO + o] = a;
  }
}

extern "C" void kernel_launch(void* const* d_in, const int* in_sizes, int n_in,
                              void* d_out, int out_size, void* d_ws, size_t ws_size,
                              hipStream_t stream) {
  // setup_inputs() order:
  // 0 x_batch 1 context_batch 2 specialist_ids 3 emb_table 4 wqkv 5 bqkv 6 wo 7 bo
  // 8 ln1_g 9 ln1_b 10 w1 11 b1 12 w2 13 b2 14 ln2_g 15 ln2_b 16 ctx_w 17 ctx_b
  // 18 ca_wq 19 ca_bq 20 ca_wk 21 ca_bk 22 ca_wv 23 ca_bv 24 ca_wo 25 ca_bo
  // 26 pred_w 27 pred_b 28 act_w 29 act_b
  k_fused<<<BB, 1024, 0, stream>>>(
      reinterpret_cast<const float*>(d_in[1]),
      reinterpret_cast<const float*>(d_in[16]),
      reinterpret_cast<const float*>(d_in[17]),
      reinterpret_cast<const float*>(d_in[22]),
      reinterpret_cast<const float*>(d_in[23]),
      reinterpret_cast<const float*>(d_in[24]),
      reinterpret_cast<const float*>(d_in[25]),
      reinterpret_cast<const int*>(d_in[2]),
      reinterpret_cast<const float*>(d_in[26]),
      reinterpret_cast<const float*>(d_in[27]),
      reinterpret_cast<const float*>(d_in[28]),
      reinterpret_cast<const float*>(d_in[29]),
      reinterpret_cast<float*>(d_out));
}

// Round 4
// 144.092 us; speedup vs baseline: 1.4515x; 1.1075x over previous
//
#include <hip/hip_runtime.h>
#include <hip/hip_bf16.h>

// Dead-code-eliminated forward (verified: passed, absmax <4e-6, fp32 inputs).
// Cross-attention has ONE key/value -> softmax == 1 -> outputs depend only on:
//   ctx  = context_batch @ ctx_w + ctx_b          (2 -> 512)
//   v    = ctx @ ca_wv + ca_bv                    (512x512)
//   last = v @ ca_wo + ca_bo                      (512x512)
//   pred = last @ pred_w[sid] + pred_b[sid]; act likewise (512x64 each)
//
// Round-3 restructure: weight-stationary, wide. Each weight element is read by
// exactly ONE block and applied to all 16 batch rows (previous design: 16
// blocks each streamed the full 2.25 MB on a single CU -> per-CU streaming
// bound at ~42 us). Three kernels, partial sums handed through d_ws with a
// deterministic two-stage reduction.

#define DD 512
#define BB 16
#define OO 64
#define NC 8   // d-chunks (reduction split) per matvec

// ---------------- K1: vpart[c][b][j] = sum_{d in chunk c} ctx[b][d]*wv[d][j] ----
// grid 64 = (jb 8 x db 8), 256 threads = (dsub 4 x j 64)
__global__ __launch_bounds__(256) void k1_v(
    const float* __restrict__ cb, const float* __restrict__ cw,
    const float* __restrict__ cbias, const float* __restrict__ wv,
    float* __restrict__ vpart) {
  __shared__ float cs[BB * 64];           // ctx[b][d-chunk]
  __shared__ float red[4 * BB * 64];      // per-dsub partials
  const int tid = threadIdx.x;
  const int jb = blockIdx.x & 7, db = blockIdx.x >> 3;
  const int d0 = db * 64, j0 = jb * 64;

  for (int idx = tid; idx < BB * 64; idx += 256) {
    const int b = idx >> 6, d = idx & 63;
    cs[idx] = fmaf(cb[2 * b], cw[d0 + d],
               fmaf(cb[2 * b + 1], cw[DD + d0 + d], cbias[d0 + d]));
  }
  __syncthreads();

  const int j = tid & 63, dsub = tid >> 6;   // dsub in [0,4), 16 d each
  float acc[BB];
#pragma unroll
  for (int b = 0; b < BB; ++b) acc[b] = 0.f;
  float wr[16];
#pragma unroll
  for (int i = 0; i < 16; ++i)
    wr[i] = wv[(d0 + dsub * 16 + i) * DD + j0 + j];
#pragma unroll
  for (int i = 0; i < 16; ++i) {
    const int d = dsub * 16 + i;
#pragma unroll
    for (int b = 0; b < BB; ++b) acc[b] = fmaf(cs[b * 64 + d], wr[i], acc[b]);
  }
#pragma unroll
  for (int b = 0; b < BB; ++b) red[dsub * (BB * 64) + b * 64 + j] = acc[b];
  __syncthreads();
  for (int idx = tid; idx < BB * 64; idx += 256) {
    float s = red[idx] + red[idx + BB * 64] + red[idx + 2 * BB * 64] + red[idx + 3 * BB * 64];
    const int b = idx >> 6, jj = idx & 63;
    vpart[(db * BB + b) * DD + j0 + jj] = s;
  }
}

// ---------------- K2: lpart[c][b][j] = sum_{d in chunk c} v[b][d]*wo[d][j] ----
// v[b][d] = bv[d] + sum_c vpart[c][b][d]
__global__ __launch_bounds__(256) void k2_o(
    const float* __restrict__ bv, const float* __restrict__ wo,
    const float* __restrict__ vpart, float* __restrict__ lpart) {
  __shared__ float vs[BB * 64];
  __shared__ float red[4 * BB * 64];
  const int tid = threadIdx.x;
  const int jb = blockIdx.x & 7, db = blockIdx.x >> 3;
  const int d0 = db * 64, j0 = jb * 64;

  for (int idx = tid; idx < BB * 64; idx += 256) {
    const int b = idx >> 6, d = idx & 63;
    float s = bv[d0 + d];
#pragma unroll
    for (int c = 0; c < NC; ++c) s += vpart[(c * BB + b) * DD + d0 + d];
    vs[idx] = s;
  }
  __syncthreads();

  const int j = tid & 63, dsub = tid >> 6;
  float acc[BB];
#pragma unroll
  for (int b = 0; b < BB; ++b) acc[b] = 0.f;
  float wr[16];
#pragma unroll
  for (int i = 0; i < 16; ++i)
    wr[i] = wo[(d0 + dsub * 16 + i) * DD + j0 + j];
#pragma unroll
  for (int i = 0; i < 16; ++i) {
    const int d = dsub * 16 + i;
#pragma unroll
    for (int b = 0; b < BB; ++b) acc[b] = fmaf(vs[b * 64 + d], wr[i], acc[b]);
  }
#pragma unroll
  for (int b = 0; b < BB; ++b) red[dsub * (BB * 64) + b * 64 + j] = acc[b];
  __syncthreads();
  for (int idx = tid; idx < BB * 64; idx += 256) {
    float s = red[idx] + red[idx + BB * 64] + red[idx + 2 * BB * 64] + red[idx + 3 * BB * 64];
    const int b = idx >> 6, jj = idx & 63;
    lpart[(db * BB + b) * DD + j0 + jj] = s;
  }
}

// ---------------- K3: heads. grid 32 = (b 16 x half 2), 512 threads ----
// last[b][d] = bo[d] + sum_c lpart[c][b][d]
__global__ __launch_bounds__(512) void k3_head(
    const float* __restrict__ bo, const float* __restrict__ lpart,
    const int* __restrict__ sid,
    const float* __restrict__ pw, const float* __restrict__ pb,
    const float* __restrict__ aw, const float* __restrict__ ab,
    float* __restrict__ out) {
  __shared__ float ls[DD];
  __shared__ float red[8 * OO];
  const int tid = threadIdx.x;
  const int b = blockIdx.x & 15, half = blockIdx.x >> 4;

  for (int d = tid; d < DD; d += 512) {
    float s = bo[d];
#pragma unroll
    for (int c = 0; c < NC; ++c) s += lpart[(c * BB + b) * DD + d];
    ls[d] = s;
  }
  __syncthreads();

  const int s = sid[b];
  const int o = tid & 63, dsub = tid >> 6;     // dsub in [0,8), 64 d each
  const float* w = (half ? aw : pw) + (s * DD + dsub * 64) * OO + o;
  float acc = 0.f;
#pragma unroll 16
  for (int i = 0; i < 64; ++i)
    acc = fmaf(ls[dsub * 64 + i], w[i * OO], acc);
  red[dsub * OO + o] = acc;
  __syncthreads();
  if (tid < OO) {
    float a = (half ? ab : pb)[s * OO + tid];
#pragma unroll
    for (int p = 0; p < 8; ++p) a += red[p * OO + tid];
    out[half * (BB * OO) + b * OO + tid] = a;
  }
}

extern "C" void kernel_launch(void* const* d_in, const int* in_sizes, int n_in,
                              void* d_out, int out_size, void* d_ws, size_t ws_size,
                              hipStream_t stream) {
  // setup_inputs() order:
  // 0 x_batch 1 context_batch 2 specialist_ids 3 emb_table 4 wqkv 5 bqkv 6 wo 7 bo
  // 8 ln1_g 9 ln1_b 10 w1 11 b1 12 w2 13 b2 14 ln2_g 15 ln2_b 16 ctx_w 17 ctx_b
  // 18 ca_wq 19 ca_bq 20 ca_wk 21 ca_bk 22 ca_wv 23 ca_bv 24 ca_wo 25 ca_bo
  // 26 pred_w 27 pred_b 28 act_w 29 act_b
  const float* cb    = reinterpret_cast<const float*>(d_in[1]);
  const int*   sid   = reinterpret_cast<const int*>(d_in[2]);
  const float* cw    = reinterpret_cast<const float*>(d_in[16]);
  const float* cbias = reinterpret_cast<const float*>(d_in[17]);
  const float* wv    = reinterpret_cast<const float*>(d_in[22]);
  const float* bv    = reinterpret_cast<const float*>(d_in[23]);
  const float* wo    = reinterpret_cast<const float*>(d_in[24]);
  const float* bo    = reinterpret_cast<const float*>(d_in[25]);
  const float* pw    = reinterpret_cast<const float*>(d_in[26]);
  const float* pb    = reinterpret_cast<const float*>(d_in[27]);
  const float* aw    = reinterpret_cast<const float*>(d_in[28]);
  const float* ab    = reinterpret_cast<const float*>(d_in[29]);

  float* vpart = reinterpret_cast<float*>(d_ws);        // [8][16][512]
  float* lpart = vpart + NC * BB * DD;                  // [8][16][512]

  k1_v   <<<64, 256, 0, stream>>>(cb, cw, cbias, wv, vpart);
  k2_o   <<<64, 256, 0, stream>>>(bv, wo, vpart, lpart);
  k3_head<<<32, 512, 0, stream>>>(bo, lpart, sid, pw, pb, aw, ab,
                                  reinterpret_cast<float*>(d_out));
}